// Round 1
// 1448.283 us; speedup vs baseline: 2.0030x; 2.0030x over previous
//
#include <hip/hip_runtime.h>

#define B_ 4
#define H_ 16
#define S_ 2048
#define D_ 64
#define SCALE_ 0.125f
#define TQ 64
#define TK 64
#define NT (S_ / TK)            // 32 k-tiles
#define LDW 72                  // f16 row stride in LDS (144 B, 16B-aligned)
#define OUT_W_OFF ((size_t)B_ * H_ * S_ * D_)   // O first, then weights

typedef _Float16 f16;
typedef __attribute__((ext_vector_type(2))) _Float16 f16x2;
typedef __attribute__((ext_vector_type(8))) _Float16 f16x8;
typedef __attribute__((ext_vector_type(16))) float   f32x16;

__global__ __launch_bounds__(256, 4)
void sdpa_fused_kernel(const float* __restrict__ Q, const float* __restrict__ K,
                       const float* __restrict__ V, const int* __restrict__ M,
                       float* __restrict__ out)
{
    __shared__ f16 Qs[TQ * LDW];
    __shared__ f16 Ks[TK * LDW];
    __shared__ f16 Vs[D_ * LDW];      // TRANSPOSED: Vs[d * LDW + k]
    __shared__ f16 Ws[TQ * LDW];
    __shared__ float lpart[2][TQ];
    __shared__ float linv[TQ];

    const int tid = threadIdx.x;
    const int w   = tid >> 6;        // wave 0..3
    const int l   = tid & 63;        // lane
    const int lc  = l & 31;
    const int lh  = l >> 5;
    const int qt  = blockIdx.x >> 6; // 0..31
    const int bh  = blockIdx.x & 63; // 0..63  (b*16+h)
    const int b   = bh >> 4;
    const int q0  = qt * TQ;

    const float* Qp = Q + (size_t)bh * S_ * D_;
    const float* Kp = K + (size_t)bh * S_ * D_;
    const float* Vp = V + (size_t)bh * S_ * D_;
    const int*   Mp = M + (size_t)b * S_ * S_;
    float* Wout = out + OUT_W_OFF + (size_t)bh * S_ * S_;
    float* Op   = out + (size_t)bh * S_ * D_;

    const int mbase = (w >> 1) * 32;   // q-rows of this wave's quadrant
    const int nbase = (w & 1) * 32;    // cols (k or d) of this wave's quadrant

    const int sr  = tid >> 4;          // staging row 0..15
    const int sc4 = (tid & 15) * 4;    // staging col*4

    // ---- staging helpers: issue-early (loadX) / write-late (writeX) ----
    float4 kreg[4], vreg[4];
    auto loadK = [&](int k0) {
        #pragma unroll
        for (int p = 0; p < 4; p++)
            kreg[p] = *(const float4*)(Kp + (size_t)(k0 + sr + p * 16) * D_ + sc4);
    };
    auto writeK = [&]() {
        #pragma unroll
        for (int p = 0; p < 4; p++) {
            const int row = sr + p * 16;
            f16x2 lo; lo[0] = (f16)kreg[p].x; lo[1] = (f16)kreg[p].y;
            f16x2 hi; hi[0] = (f16)kreg[p].z; hi[1] = (f16)kreg[p].w;
            *(f16x2*)(&Ks[row * LDW + sc4])     = lo;
            *(f16x2*)(&Ks[row * LDW + sc4 + 2]) = hi;
        }
    };
    auto loadV = [&](int k0) {
        #pragma unroll
        for (int p = 0; p < 4; p++)
            vreg[p] = *(const float4*)(Vp + (size_t)(k0 + sr + p * 16) * D_ + sc4);
    };
    auto writeV = [&]() {               // transpose into Vs[d][k]
        #pragma unroll
        for (int p = 0; p < 4; p++) {
            const int row = sr + p * 16;   // k-index within tile
            Vs[(sc4 + 0) * LDW + row] = (f16)vreg[p].x;
            Vs[(sc4 + 1) * LDW + row] = (f16)vreg[p].y;
            Vs[(sc4 + 2) * LDW + row] = (f16)vreg[p].z;
            Vs[(sc4 + 3) * LDW + row] = (f16)vreg[p].w;
        }
    };

    // ---- stage Q tile (once) + first K tile ----
    {
        #pragma unroll
        for (int p = 0; p < 4; p++) {
            const int row = sr + p * 16;
            const float4 v = *(const float4*)(Qp + (size_t)(q0 + row) * D_ + sc4);
            f16x2 lo; lo[0] = (f16)v.x; lo[1] = (f16)v.y;
            f16x2 hi; hi[0] = (f16)v.z; hi[1] = (f16)v.w;
            *(f16x2*)(&Qs[row * LDW + sc4])     = lo;
            *(f16x2*)(&Qs[row * LDW + sc4 + 2]) = hi;
        }
    }
    loadK(0);
    writeK();
    __syncthreads();   // Qs + Ks(0) ready

    float rsum[16];
    #pragma unroll
    for (int r = 0; r < 16; r++) rsum[r] = 0.f;
    // mask bit-cache: bit t of mbits[r] = mask(row r, this lane's col, tile t)
    unsigned mbits[16];
    #pragma unroll
    for (int r = 0; r < 16; r++) mbits[r] = 0u;

    // ================= phase 1: softmax denominators =================
    for (int t = 0; t < NT; t++) {
        const int kg = t * TK + nbase + lc;
        if (t + 1 < NT) loadK((t + 1) * TK);   // issue next K early

        int mreg[16];
        #pragma unroll
        for (int r = 0; r < 16; r++) {
            const int rowg = q0 + mbase + ((r & 3) + 8 * (r >> 2) + 4 * lh);
            mreg[r] = Mp[(size_t)rowg * S_ + kg];
        }

        f32x16 acc;
        #pragma unroll
        for (int i = 0; i < 16; i++) acc[i] = 0.f;
        __builtin_amdgcn_s_setprio(1);
        #pragma unroll
        for (int s = 0; s < 4; s++) {
            f16x8 af = *(const f16x8*)(&Qs[(mbase + lc) * LDW + lh * 8 + s * 16]);
            f16x8 bf = *(const f16x8*)(&Ks[(nbase + lc) * LDW + lh * 8 + s * 16]);
            acc = __builtin_amdgcn_mfma_f32_32x32x16_f16(af, bf, acc, 0, 0, 0);
        }
        __builtin_amdgcn_s_setprio(0);

        #pragma unroll
        for (int r = 0; r < 16; r++) {
            const float e = __expf(acc[r] * SCALE_);
            rsum[r] += mreg[r] ? e : 0.f;
            mbits[r] |= (unsigned)(mreg[r] != 0) << t;
        }

        __syncthreads();                 // all QK reads of Ks(t) done
        if (t + 1 < NT) writeK();        // publish Ks(t+1)
        __syncthreads();                 // Ks(t+1) visible
    }

    // ---- reduce row sums across the 32 columns held by this wave ----
    #pragma unroll
    for (int r = 0; r < 16; r++) {
        float v = rsum[r];
        v += __shfl_xor(v, 1, 64);
        v += __shfl_xor(v, 2, 64);
        v += __shfl_xor(v, 4, 64);
        v += __shfl_xor(v, 8, 64);
        v += __shfl_xor(v, 16, 64);
        if (lc == 0) lpart[w & 1][mbase + ((r & 3) + 8 * (r >> 2) + 4 * lh)] = v;
    }
    __syncthreads();
    if (tid < TQ) linv[tid] = 1.0f / (lpart[0][tid] + lpart[1][tid]);
    __syncthreads();
    float invr[16];
    #pragma unroll
    for (int r = 0; r < 16; r++)
        invr[r] = linv[mbase + ((r & 3) + 8 * (r >> 2) + 4 * lh)];

    // ================= phase 2: weights + O = W*V =================
    f32x16 acco;
    #pragma unroll
    for (int i = 0; i < 16; i++) acco[i] = 0.f;

    loadK(0); loadV(0);
    writeK(); writeV();      // safe: all waves past phase-1 Ks reads (linv barriers)
    __syncthreads();         // Ks(0), Vs(0) ready

    for (int t = 0; t < NT; t++) {
        const int kg = t * TK + nbase + lc;
        if (t + 1 < NT) { loadK((t + 1) * TK); loadV((t + 1) * TK); }  // issue early

        f32x16 acc;
        #pragma unroll
        for (int i = 0; i < 16; i++) acc[i] = 0.f;
        __builtin_amdgcn_s_setprio(1);
        #pragma unroll
        for (int s = 0; s < 4; s++) {
            f16x8 af = *(const f16x8*)(&Qs[(mbase + lc) * LDW + lh * 8 + s * 16]);
            f16x8 bf = *(const f16x8*)(&Ks[(nbase + lc) * LDW + lh * 8 + s * 16]);
            acc = __builtin_amdgcn_mfma_f32_32x32x16_f16(af, bf, acc, 0, 0, 0);
        }
        __builtin_amdgcn_s_setprio(0);

        #pragma unroll
        for (int r = 0; r < 16; r++) {
            const int row_l = mbase + ((r & 3) + 8 * (r >> 2) + 4 * lh);
            const float e = __expf(acc[r] * SCALE_) * invr[r];
            const float wgt = ((mbits[r] >> t) & 1u) ? e : 0.f;
            __builtin_nontemporal_store(wgt, &Wout[(size_t)(q0 + row_l) * S_ + kg]);
            Ws[row_l * LDW + nbase + lc] = (f16)wgt;
        }

        __syncthreads();                 // S2: Ws ready; all QK reads of Ks done
        if (t + 1 < NT) writeK();        // overlaps PV (no Ks readers until next QK)

        __builtin_amdgcn_s_setprio(1);
        #pragma unroll
        for (int s = 0; s < 4; s++) {
            f16x8 af = *(const f16x8*)(&Ws[(mbase + lc) * LDW + lh * 8 + s * 16]);
            f16x8 bf = *(const f16x8*)(&Vs[(nbase + lc) * LDW + lh * 8 + s * 16]);
            acco = __builtin_amdgcn_mfma_f32_32x32x16_f16(af, bf, acco, 0, 0, 0);
        }
        __builtin_amdgcn_s_setprio(0);

        __syncthreads();                 // S3: Vs/Ws reads done
        if (t + 1 < NT) writeV();        // next iter's S2 publishes before PV reads
    }

    // ---- store O (already normalized: wgt included 1/l) ----
    #pragma unroll
    for (int r = 0; r < 16; r++) {
        const int rowg = q0 + mbase + ((r & 3) + 8 * (r >> 2) + 4 * lh);
        __builtin_nontemporal_store(acco[r], &Op[(size_t)rowg * D_ + nbase + lc]);
    }
}

extern "C" void kernel_launch(void* const* d_in, const int* in_sizes, int n_in,
                              void* d_out, int out_size, void* d_ws, size_t ws_size,
                              hipStream_t stream) {
    const float* Q = (const float*)d_in[0];
    const float* K = (const float*)d_in[1];
    const float* V = (const float*)d_in[2];
    const int*   M = (const int*)d_in[3];
    float* out = (float*)d_out;
    (void)in_sizes; (void)n_in; (void)out_size; (void)d_ws; (void)ws_size;

    const int grid = (S_ / TQ) * B_ * H_;   // 32 q-tiles * 64 (b,h) = 2048 blocks
    sdpa_fused_kernel<<<dim3(grid), dim3(256), 0, stream>>>(Q, K, V, M, out);
}